// Round 8
// baseline (1018.658 us; speedup 1.0000x reference)
//
#include <hip/hip_runtime.h>
#include <type_traits>
#include <cstdint>
#include <cstddef>

#define L_SEQ 4800
#define DMODEL 256
#define BS 8
#define MROWS (BS*L_SEQ)          // 38400
#define PERBATCH (L_SEQ*DMODEL)   // 1228800
#define KVSET 67584               // 65536 KV + 2048 Ksum floats per mode

typedef __attribute__((ext_vector_type(8))) short bfrag8;
typedef __attribute__((ext_vector_type(4))) float floatx4;

// ---------- helpers ----------
__device__ __forceinline__ float bf2f(unsigned short u){
  union { unsigned int i; float f; } x; x.i = ((unsigned int)u) << 16; return x.f;
}
__device__ __forceinline__ unsigned short f2bf(float f){
  union { float f; unsigned int i; } x; x.f = f;
  x.i += 0x7fff + ((x.i >> 16) & 1);   // RNE
  return (unsigned short)(x.i >> 16);
}
__device__ __forceinline__ float phi(float x){
  return x > 0.f ? x + 1.f : __expf(x);
}
__device__ __forceinline__ void gll16(const void* g, void* l){
  __builtin_amdgcn_global_load_lds((const __attribute__((address_space(1))) unsigned int*)g,
      (__attribute__((address_space(3))) unsigned int*)l, 16, 0, 0);
}

// ---------- MFMA GEMM (projections): C[M,N] = A[M,K] @ Bt[N,K]^T ----------
template<typename TC, bool RELU>
__global__ __launch_bounds__(256) void gemm_mfma(const unsigned short* __restrict__ A,
                                                 const unsigned short* __restrict__ Bt,
                                                 TC* __restrict__ C, int M, int N, int K){
  __shared__ unsigned short Al[2][4096];   // [buf][128 rows][32 k]
  __shared__ unsigned short Bl[2][4096];
  const int tid  = threadIdx.x;
  const int lane = tid & 63;
  const int wave = tid >> 6;
  const int row0 = blockIdx.y << 7;
  const int col0 = blockIdx.x << 7;
  const int wr0  = (wave & 1) << 6;
  const int wc0  = (wave >> 1) << 6;
  const int m = lane & 15, q = lane >> 4;
  const int sw = (m >> 1) & 3;

  floatx4 acc[4][4] = {};

  const int u0 = tid, u1 = tid + 256;
  const int r0 = u0 >> 2, s0 = u0 & 3;
  const int r1 = u1 >> 2, s1 = u1 & 3;

  auto stage = [&](int k0, int b){
    gll16(A  + (size_t)(row0 + r0)*K + k0 + ((s0 ^ ((r0 >> 1) & 3)) << 3), Al[b] + (size_t)u0*8);
    gll16(A  + (size_t)(row0 + r1)*K + k0 + ((s1 ^ ((r1 >> 1) & 3)) << 3), Al[b] + (size_t)u1*8);
    gll16(Bt + (size_t)(col0 + r0)*K + k0 + ((s0 ^ ((r0 >> 1) & 3)) << 3), Bl[b] + (size_t)u0*8);
    gll16(Bt + (size_t)(col0 + r1)*K + k0 + ((s1 ^ ((r1 >> 1) & 3)) << 3), Bl[b] + (size_t)u1*8);
  };

  stage(0, 0);
  const int nk = K >> 5;
  for (int ks = 0; ks < nk; ks++){
    asm volatile("s_waitcnt vmcnt(0) lgkmcnt(0)" ::: "memory");
    __builtin_amdgcn_s_barrier();
    asm volatile("" ::: "memory");
    if (ks < nk - 1) stage((ks + 1) << 5, (ks + 1) & 1);
    const unsigned short* ab = Al[ks & 1];
    const unsigned short* bb = Bl[ks & 1];
    bfrag8 af[4], bf[4];
    #pragma unroll
    for (int t = 0; t < 4; t++){
      af[t] = *(const bfrag8*)(ab + (size_t)(wr0 + t*16 + m)*32 + ((q ^ sw) << 3));
      bf[t] = *(const bfrag8*)(bb + (size_t)(wc0 + t*16 + m)*32 + ((q ^ sw) << 3));
    }
    #pragma unroll
    for (int mt = 0; mt < 4; mt++)
      #pragma unroll
      for (int nt = 0; nt < 4; nt++)
        acc[mt][nt] = __builtin_amdgcn_mfma_f32_16x16x32_bf16(af[mt], bf[nt], acc[mt][nt], 0, 0, 0);
  }

  #pragma unroll
  for (int mt = 0; mt < 4; mt++){
    #pragma unroll
    for (int nt = 0; nt < 4; nt++){
      const int col  = col0 + wc0 + nt*16 + m;
      const int rowb = row0 + wr0 + mt*16 + q*4;
      #pragma unroll
      for (int i = 0; i < 4; i++){
        float v = acc[mt][nt][i];
        if (RELU) v = v > 0.f ? v : 0.f;
        if constexpr (std::is_same<TC,float>::value) C[(size_t)(rowb+i)*N + col] = v;
        else                                         C[(size_t)(rowb+i)*N + col] = f2bf(v);
      }
    }
  }
}

// ---------- unified big GEMM: 128x256 tile, 512 threads (8 waves), db BK=32, drain-at-top ----------
// MODE 0 (Wm):  K=256. A = blockIdx.z ? A1 : A0 (stride 256). out = LN -> bf16 ob{0,1} (stride 256).
// MODE 1 (W2):  K=512. A = A0 (hid, stride 512). out = LN -> macc (+add), stride 256.
// MODE 2 (W1):  K=512. A k-split: ks<8 -> A0 (xc, stride 256) else A1 (msgln, stride 256).
//               out = relu -> bf16 ob0 (stride 512), col0 = blockIdx.x*256.
template<int MODE, int NK>
__global__ __launch_bounds__(512) void gemm3(const unsigned short* __restrict__ A0,
                                             const unsigned short* __restrict__ A1,
                                             const unsigned short* __restrict__ Bt,
                                             const float* __restrict__ g,
                                             const float* __restrict__ b,
                                             unsigned short* __restrict__ ob0,
                                             unsigned short* __restrict__ ob1,
                                             float* __restrict__ of,
                                             int add){
  __shared__ unsigned short Al[2][4096];    // [buf][128 r][32 k]
  __shared__ unsigned short Bl[2][8192];    // [buf][256 c][32 k]
  __shared__ float2 LNp[128][4];
  __shared__ float2 LNmu[128];
  const int tid  = threadIdx.x;
  const int lane = tid & 63;
  const int wave = tid >> 6;
  const int row0 = blockIdx.y << 7;
  const int col0 = (MODE == 2) ? (blockIdx.x << 8) : 0;
  const int wr0  = (wave & 1) << 6;
  const int wc0  = (wave >> 1) << 6;
  const int m = lane & 15, q = lane >> 4;
  const int sw = (m >> 1) & 3;
  constexpr int AST = (MODE == 1) ? 512 : 256;
  constexpr int BST = (MODE == 0) ? 256 : 512;

  const unsigned short* Asel = (MODE == 0 && blockIdx.z) ? A1 : A0;
  unsigned short* ob = (MODE == 0 && blockIdx.z) ? ob1 : ob0;

  const int ra = tid >> 2, sa = tid & 3;

  auto stage = [&](int ks, int bsel){
    const int k0 = ks << 5;
    const unsigned short* As;
    int aoff;
    if constexpr (MODE == 2){ As = (ks < 8) ? A0 : A1; aoff = k0 & 255; }
    else                    { As = Asel;               aoff = k0; }
    gll16(As + (size_t)(row0 + ra)*AST + aoff + ((sa ^ ((ra >> 1) & 3)) << 3),
          Al[bsel] + (size_t)tid*8);
    #pragma unroll
    for (int i = 0; i < 2; i++){
      int u = (i << 9) + tid;
      int c = u >> 2, sc = u & 3;
      gll16(Bt + (size_t)(col0 + c)*BST + k0 + ((sc ^ ((c >> 1) & 3)) << 3),
            Bl[bsel] + (size_t)u*8);
    }
  };

  floatx4 acc[4][4] = {};
  stage(0, 0);
  for (int ks = 0; ks < NK; ks++){
    asm volatile("s_waitcnt vmcnt(0) lgkmcnt(0)" ::: "memory");
    __builtin_amdgcn_s_barrier();
    asm volatile("" ::: "memory");
    if (ks < NK - 1) stage(ks + 1, (ks + 1) & 1);
    const unsigned short* ab = Al[ks & 1];
    const unsigned short* bb = Bl[ks & 1];
    bfrag8 af[4], bf[4];
    #pragma unroll
    for (int t = 0; t < 4; t++){
      af[t] = *(const bfrag8*)(ab + (size_t)(wr0 + t*16 + m)*32 + ((q ^ sw) << 3));
      bf[t] = *(const bfrag8*)(bb + (size_t)(wc0 + t*16 + m)*32 + ((q ^ sw) << 3));
    }
    #pragma unroll
    for (int mt = 0; mt < 4; mt++)
      #pragma unroll
      for (int nt = 0; nt < 4; nt++)
        acc[mt][nt] = __builtin_amdgcn_mfma_f32_16x16x32_bf16(af[mt], bf[nt], acc[mt][nt], 0, 0, 0);
  }

  if constexpr (MODE == 2){
    // relu -> bf16, stride 512
    #pragma unroll
    for (int mt = 0; mt < 4; mt++){
      #pragma unroll
      for (int nt = 0; nt < 4; nt++){
        const int col  = col0 + wc0 + nt*16 + m;
        const int rowb = row0 + wr0 + mt*16 + q*4;
        #pragma unroll
        for (int i = 0; i < 4; i++){
          float v = acc[mt][nt][i];
          v = v > 0.f ? v : 0.f;
          ob[(size_t)(rowb+i)*512 + col] = f2bf(v);
        }
      }
    }
  } else {
    // ---- LN over 256 cols: per-wave partials (cols wc0..wc0+64) merged across 4 col-groups ----
    const int cg = wave >> 1;
    #pragma unroll
    for (int mt = 0; mt < 4; mt++)
      #pragma unroll
      for (int i = 0; i < 4; i++){
        float s = 0.f, qq = 0.f;
        #pragma unroll
        for (int nt = 0; nt < 4; nt++){ float v = acc[mt][nt][i]; s += v; qq += v*v; }
        #pragma unroll
        for (int o = 1; o < 16; o <<= 1){ s += __shfl_xor(s, o, 64); qq += __shfl_xor(qq, o, 64); }
        if (m == 0){
          int row = wr0 + mt*16 + q*4 + i;
          float2* p = &LNp[row][cg];
          // two waves (wave&1 pairs) share cg but different rows -> no conflict
          *p = make_float2(s, qq);
        }
      }
    __syncthreads();
    if (tid < 128){
      float2 p0 = LNp[tid][0], p1 = LNp[tid][1], p2 = LNp[tid][2], p3 = LNp[tid][3];
      float S = p0.x + p1.x + p2.x + p3.x;
      float Q = p0.y + p1.y + p2.y + p3.y;
      float mean = S * (1.f/256.f);
      float var  = Q * (1.f/256.f) - mean*mean;
      LNmu[tid] = make_float2(mean, rsqrtf(var + 1e-5f));
    }
    __syncthreads();

    float gv[4], bv[4];
    #pragma unroll
    for (int nt = 0; nt < 4; nt++){ int col = wc0 + nt*16 + m; gv[nt] = g[col]; bv[nt] = b[col]; }
    #pragma unroll
    for (int mt = 0; mt < 4; mt++)
      #pragma unroll
      for (int i = 0; i < 4; i++){
        int row = wr0 + mt*16 + q*4 + i;
        float2 ms = LNmu[row];
        const size_t rowg = row0 + row;
        #pragma unroll
        for (int nt = 0; nt < 4; nt++){
          int col = wc0 + nt*16 + m;
          float y = (acc[mt][nt][i] - ms.x) * ms.y * gv[nt] + bv[nt];
          if constexpr (MODE == 0){
            ob[rowg*256 + col] = f2bf(y);
          } else {
            float* p = of + rowg*256 + col;
            if (add) y += *p;
            *p = y;
          }
        }
      }
  }
}

// ---------- one-time converts ----------
__global__ __launch_bounds__(256) void wconv(const float* __restrict__ W, unsigned short* __restrict__ Wt,
                                             int kshift, int N){
  int idx = blockIdx.x*256 + threadIdx.x;
  int kk = idx & ((1 << kshift) - 1);
  int nn = idx >> kshift;
  Wt[idx] = f2bf(W[(size_t)kk*N + nn]);
}
__global__ __launch_bounds__(256) void conv_bf16(const float* __restrict__ in, unsigned short* __restrict__ out){
  int i = blockIdx.x*256 + threadIdx.x;
  float4 v = ((const float4*)in)[i];
  ushort4 o; o.x = f2bf(v.x); o.y = f2bf(v.y); o.z = f2bf(v.z); o.w = f2bf(v.w);
  ((ushort4*)out)[i] = o;
}

// ---------- permute materializers ----------
__global__ __launch_bounds__(256) void permute1(const unsigned short* __restrict__ sA, unsigned short* __restrict__ dA,
                                                const unsigned short* __restrict__ sB, unsigned short* __restrict__ dB){
  const unsigned short* s = blockIdx.z ? sB : sA;
  unsigned short*       d = blockIdx.z ? dB : dA;
  __shared__ unsigned short tile[1024];
  const int t = threadIdx.x;
  const size_t base = (size_t)blockIdx.x * 1024;
  #pragma unroll
  for (int i = 0; i < 4; i++) tile[i*256 + t] = s[base + i*256 + t];
  __syncthreads();
  const int pg = ((t & 7) << 5) + (t >> 3);
  #pragma unroll
  for (int i = 0; i < 4; i++) d[base + i*256 + t] = tile[i*256 + pg];
}

__global__ __launch_bounds__(256) void permute2(const unsigned short* __restrict__ sA, unsigned short* __restrict__ dA,
                                                const unsigned short* __restrict__ sB, unsigned short* __restrict__ dB){
  const unsigned short* s = blockIdx.z ? sB : sA;
  unsigned short*       d = blockIdx.z ? dB : dA;
  __shared__ unsigned short tile[64*256];
  const int t = threadIdx.x;
  const int rr0 = blockIdx.x * 64;
  const size_t boff = (size_t)blockIdx.y * PERBATCH;
  #pragma unroll
  for (int i = 0; i < 16; i++){
    int u = i*256 + t;
    *(ushort4*)&tile[u*4] = *(const ushort4*)&s[boff + (size_t)rr0*256 + (size_t)u*4];
  }
  __syncthreads();
  #pragma unroll
  for (int i = 0; i < 8; i++){
    #pragma unroll
    for (int w = 0; w < 2; w++){
      int u = w*256 + t;
      int rr = u >> 3, c4 = (u & 7) << 2;
      ushort4 v = *(const ushort4*)&tile[rr*256 + i*32 + c4];
      *(ushort4*)&d[boff + (size_t)i*153600 + (size_t)rr0*32 + (size_t)u*4] = v;
    }
  }
}

__global__ __launch_bounds__(256) void permute3(const unsigned short* __restrict__ sA, unsigned short* __restrict__ dA,
                                                const unsigned short* __restrict__ sB, unsigned short* __restrict__ dB){
  const unsigned short* s = blockIdx.z ? sB : sA;
  unsigned short*       d = blockIdx.z ? dB : dA;
  __shared__ unsigned short tile[64*258];
  const int t = threadIdx.x;
  const int ll0 = blockIdx.x * 64;
  const size_t boff = (size_t)blockIdx.y * PERBATCH;
  #pragma unroll
  for (int i = 0; i < 32; i++){
    int u = i*256 + t;
    int row = u >> 7, col = (u & 127) << 1;
    *(ushort2*)&tile[row*258 + col] = *(const ushort2*)&s[boff + (size_t)(ll0+row)*256 + col];
  }
  __syncthreads();
  const int cw = t >> 6;
  const int ll = t & 63;
  #pragma unroll
  for (int cc = 0; cc < 256; cc += 4){
    int c = cc + cw;
    int sigma = ((c & 31) << 3) + (c >> 5);
    d[boff + (size_t)sigma*4800 + ll0 + ll] = tile[ll*258 + c];
  }
}

// ---------- attention phase A (KV/Ksum stats) ----------
__global__ __launch_bounds__(256) void attn_stats(const unsigned short* __restrict__ kq,
                                                  const unsigned short* __restrict__ vq,
                                                  float* __restrict__ KV, float* __restrict__ Ksum){
  const int chunk = blockIdx.x, h = blockIdx.y, n = blockIdx.z;
  const int t = threadIdx.x;
  const int d = t >> 3;
  const int w4 = (t & 7) << 2;
  const size_t boff = (size_t)n * PERBATCH;
  __shared__ float kb[8][32], vb[8][32];
  const int lr = t >> 5, lj = t & 31;
  float a0=0.f, a1=0.f, a2=0.f, a3=0.f, ks=0.f;
  const int s0 = chunk * 240;
  for (int s = s0; s < s0 + 240; s += 8){
    int srci = (s + lr)*256 + (h << 5) + lj;
    kb[lr][lj] = phi(bf2f(kq[boff + srci]));
    vb[lr][lj] = bf2f(vq[boff + srci]);
    __syncthreads();
    #pragma unroll
    for (int r = 0; r < 8; r++){
      float kd = kb[r][d];
      ks += kd;
      a0 += kd * vb[r][w4+0];
      a1 += kd * vb[r][w4+1];
      a2 += kd * vb[r][w4+2];
      a3 += kd * vb[r][w4+3];
    }
    __syncthreads();
  }
  float* kvp = KV + (size_t)((((n<<3)+h)<<5) + d)*32 + w4;
  atomicAdd(kvp+0, a0);
  atomicAdd(kvp+1, a1);
  atomicAdd(kvp+2, a2);
  atomicAdd(kvp+3, a3);
  if ((t & 7) == 0) atomicAdd(Ksum + (((n<<3)+h)<<5) + d, ks);
}

// ---------- attention phase B: 16 rows/block, KV cached in LDS (R0 proven) ----------
__global__ __launch_bounds__(256) void attn_apply(const unsigned short* __restrict__ qq,
                                                  const float* __restrict__ KV,
                                                  const float* __restrict__ Ksum,
                                                  unsigned short* __restrict__ msg){
  __shared__ float kvs[8192];   // [h][dd][w]
  __shared__ float kss[256];    // [h][dd]
  __shared__ float Qs[4096];    // [r][256], phi-applied
  const int t = threadIdx.x;
  const int n = blockIdx.y;
  const int row0 = blockIdx.x << 4;
  const size_t boff = (size_t)n * PERBATCH;

  #pragma unroll
  for (int i = 0; i < 32; i++) kvs[i*256 + t] = KV[(size_t)n*8192 + i*256 + t];
  kss[t] = Ksum[n*256 + t];
  #pragma unroll
  for (int r = 0; r < 16; r++)
    Qs[r*256 + t] = phi(bf2f(qq[boff + (size_t)(row0 + r)*256 + t]));
  __syncthreads();

  const int h = t >> 5, w = t & 31;
  const float* kvh = kvs + h*1024;
  const float* ksh = kss + h*32;
  float acc[16], den[16];
  #pragma unroll
  for (int r = 0; r < 16; r++){ acc[r] = 0.f; den[r] = 1e-6f; }

  #pragma unroll
  for (int d4 = 0; d4 < 8; d4++){
    const float k0 = kvh[(d4*4+0)*32 + w];
    const float k1 = kvh[(d4*4+1)*32 + w];
    const float k2 = kvh[(d4*4+2)*32 + w];
    const float k3 = kvh[(d4*4+3)*32 + w];
    const float s0 = ksh[d4*4+0], s1 = ksh[d4*4+1], s2 = ksh[d4*4+2], s3 = ksh[d4*4+3];
    #pragma unroll
    for (int r = 0; r < 16; r++){
      float4 qv = *(const float4*)&Qs[r*256 + h*32 + d4*4];
      acc[r] += qv.x*k0 + qv.y*k1 + qv.z*k2 + qv.w*k3;
      den[r] += qv.x*s0 + qv.y*s1 + qv.z*s2 + qv.w*s3;
    }
  }
  #pragma unroll
  for (int r = 0; r < 16; r++)
    msg[boff + (size_t)(row0 + r)*256 + t] = f2bf(acc[r]/den[r]);
}

// ---------- elementwise ----------
__global__ __launch_bounds__(256) void xmid_k(const float* __restrict__ x, const float* __restrict__ macc,
                                              float* __restrict__ xmid, unsigned short* __restrict__ xcbf){
  size_t i = (size_t)blockIdx.x*256 + threadIdx.x;
  float v = x[i] + 0.5f*macc[i];
  xmid[i] = v;
  xcbf[i] = f2bf(v);
}
__global__ __launch_bounds__(256) void final_k(float* __restrict__ out, const float* __restrict__ macc){
  size_t i = (size_t)blockIdx.x*256 + threadIdx.x;
  out[i] = out[i] + 0.5f*macc[i];
}
__global__ __launch_bounds__(256) void zero_k(float* __restrict__ p, int n){
  int i = blockIdx.x*256 + threadIdx.x;
  if (i < n) p[i] = 0.f;
}

// ---------- orchestration ----------
extern "C" void kernel_launch(void* const* d_in, const int* in_sizes, int n_in,
                              void* d_out, int out_size, void* d_ws, size_t ws_size,
                              hipStream_t stream){
  const float* x   = (const float*)d_in[0];
  const float* src = (const float*)d_in[1];
  const float* Wq  = (const float*)d_in[2];
  const float* Wk  = (const float*)d_in[3];
  const float* Wv  = (const float*)d_in[4];
  const float* Wm  = (const float*)d_in[5];
  const float* W1  = (const float*)d_in[6];
  const float* W2  = (const float*)d_in[7];
  const float* g1  = (const float*)d_in[8];
  const float* b1  = (const float*)d_in[9];
  const float* g2  = (const float*)d_in[10];
  const float* b2  = (const float*)d_in[11];
  float* out = (float*)d_out;

  char* ws = (char*)d_ws;
  size_t off = 0;
  auto alloc = [&](size_t bytes) -> void* {
    void* p = ws + off;
    off += (bytes + 255) & ~(size_t)255;
    return p;
  };
  unsigned short* qB   = (unsigned short*)alloc((size_t)MROWS*256*2);
  unsigned short* kB   = (unsigned short*)alloc((size_t)MROWS*256*2);   // msg slot A / hid lo
  unsigned short* vB   = (unsigned short*)alloc((size_t)MROWS*256*2);   // msg slot B / hid hi
  unsigned short* mlnB = (unsigned short*)alloc((size_t)MROWS*512*2);   // msgln0 | msgln1
  float* t1   = (float*)alloc((size_t)MROWS*256*4);                     // srcbf/qP | xbf/xc
  float* macc = (float*)alloc((size_t)MROWS*256*4);
  float* KV4  = (float*)alloc((size_t)4*KVSET*4);
  unsigned short* WqT = (unsigned short*)alloc((size_t)256*256*2);
  unsigned short* WkT = (unsigned short*)alloc((size_t)256*256*2);
  unsigned short* WvT = (unsigned short*)alloc((size_t)256*256*2);
  unsigned short* WmT = (unsigned short*)alloc((size_t)256*256*2);
  unsigned short* W1T = (unsigned short*)alloc((size_t)512*512*2);
  unsigned short* W2T = (unsigned short*)alloc((size_t)256*512*2);
  (void)ws_size; (void)in_sizes; (void)n_in; (void)out_size;

  unsigned short* srcbf  = (unsigned short*)t1;
  unsigned short* xcbf   = srcbf + (size_t)MROWS*256;    // x bf16, later xmid bf16
  unsigned short* qP     = (unsigned short*)t1;          // reuses srcbf slot after projections
  unsigned short* msgln0 = mlnB;
  unsigned short* msgln1 = mlnB + (size_t)MROWS*256;
  unsigned short* hid    = kB;                           // 39.3MB spanning kB+vB
  float* xmid = out;

  const dim3 blk(256);
  const dim3 blk512(512);

  wconv<<<dim3(256),  blk, 0, stream>>>(Wq, WqT, 8, 256);
  wconv<<<dim3(256),  blk, 0, stream>>>(Wk, WkT, 8, 256);
  wconv<<<dim3(256),  blk, 0, stream>>>(Wv, WvT, 8, 256);
  wconv<<<dim3(256),  blk, 0, stream>>>(Wm, WmT, 8, 256);
  wconv<<<dim3(1024), blk, 0, stream>>>(W1, W1T, 9, 512);
  wconv<<<dim3(512),  blk, 0, stream>>>(W2, W2T, 9, 256);
  conv_bf16<<<dim3(9600), blk, 0, stream>>>(src, srcbf);
  conv_bf16<<<dim3(9600), blk, 0, stream>>>(x,   xcbf);

  gemm_mfma<unsigned short, false><<<dim3(2,300), blk, 0, stream>>>(xcbf,  WqT, qB, MROWS, 256, 256);
  gemm_mfma<unsigned short, false><<<dim3(2,300), blk, 0, stream>>>(srcbf, WkT, kB, MROWS, 256, 256);
  gemm_mfma<unsigned short, false><<<dim3(2,300), blk, 0, stream>>>(srcbf, WvT, vB, MROWS, 256, 256);

  // all-mode stats upfront; permuted k/v live in macc space (dead until gemm3<1>)
  unsigned short* kP = (unsigned short*)macc;
  unsigned short* vP = kP + (size_t)MROWS*256;
  zero_k<<<dim3(1056), blk, 0, stream>>>(KV4, 4*KVSET);
  attn_stats<<<dim3(20,8,8), blk, 0, stream>>>(kB, vB, KV4 + 0*KVSET, KV4 + 0*KVSET + 65536);
  permute1<<<dim3(9600,1,2), blk, 0, stream>>>(kB, kP, vB, vP);
  attn_stats<<<dim3(20,8,8), blk, 0, stream>>>(kP, vP, KV4 + 1*KVSET, KV4 + 1*KVSET + 65536);
  permute2<<<dim3(75,8,2),  blk, 0, stream>>>(kB, kP, vB, vP);
  attn_stats<<<dim3(20,8,8), blk, 0, stream>>>(kP, vP, KV4 + 2*KVSET, KV4 + 2*KVSET + 65536);
  permute3<<<dim3(75,8,2),  blk, 0, stream>>>(kB, kP, vB, vP);
  attn_stats<<<dim3(20,8,8), blk, 0, stream>>>(kP, vP, KV4 + 3*KVSET, KV4 + 3*KVSET + 65536);

  auto run_pair = [&](int modeA, int modeB, int addA){
    // attention for both modes of the pair -> msg in kB / vB
    {
      const float* KV   = KV4 + (size_t)modeA*KVSET;
      const unsigned short* qsrc = qB;
      if (modeA == 2){ permute2<<<dim3(75,8,1), blk, 0, stream>>>(qB, qP, nullptr, nullptr); qsrc = qP; }
      attn_apply<<<dim3(300,BS), blk, 0, stream>>>(qsrc, KV, KV + 65536, kB);
    }
    {
      const float* KV   = KV4 + (size_t)modeB*KVSET;
      if (modeB == 1)      permute1<<<dim3(9600,1,1), blk, 0, stream>>>(qB, qP, nullptr, nullptr);
      else                 permute3<<<dim3(75,8,1),   blk, 0, stream>>>(qB, qP, nullptr, nullptr);
      attn_apply<<<dim3(300,BS), blk, 0, stream>>>(qP, KV, KV + 65536, vB);
    }
    // merged Wm GEMM + LN for both modes -> msgln0/msgln1
    gemm3<0,8><<<dim3(1,300,2), blk512, 0, stream>>>(kB, vB, WmT, g1, b1, msgln0, msgln1, nullptr, 0);
    // FFN chains (serial: hid buffer shared)
    gemm3<2,16><<<dim3(2,300), blk512, 0, stream>>>(xcbf, msgln0, W1T, nullptr, nullptr, hid, nullptr, nullptr, 0);
    gemm3<1,16><<<dim3(1,300), blk512, 0, stream>>>(hid, nullptr, W2T, g2, b2, nullptr, nullptr, macc, addA);
    gemm3<2,16><<<dim3(2,300), blk512, 0, stream>>>(xcbf, msgln1, W1T, nullptr, nullptr, hid, nullptr, nullptr, 0);
    gemm3<1,16><<<dim3(1,300), blk512, 0, stream>>>(hid, nullptr, W2T, g2, b2, nullptr, nullptr, macc, 1);
  };

  run_pair(0, 1, 0);                                            // m, m3
  xmid_k<<<dim3(MROWS), blk, 0, stream>>>(x, macc, xmid, xcbf); // xmid + xc update
  run_pair(2, 3, 0);                                            // m1, m2
  final_k<<<dim3(MROWS), blk, 0, stream>>>(out, macc);
}

// Round 9
// 914.090 us; speedup vs baseline: 1.1144x; 1.1144x over previous
//
#include <hip/hip_runtime.h>
#include <type_traits>
#include <cstdint>
#include <cstddef>

#define L_SEQ 4800
#define DMODEL 256
#define BS 8
#define MROWS (BS*L_SEQ)          // 38400
#define PERBATCH (L_SEQ*DMODEL)   // 1228800
#define KVSET 67584               // 65536 KV + 2048 Ksum floats per mode

typedef __attribute__((ext_vector_type(8))) short bfrag8;
typedef __attribute__((ext_vector_type(4))) float floatx4;

// ---------- helpers ----------
__device__ __forceinline__ float bf2f(unsigned short u){
  union { unsigned int i; float f; } x; x.i = ((unsigned int)u) << 16; return x.f;
}
__device__ __forceinline__ unsigned short f2bf(float f){
  union { float f; unsigned int i; } x; x.f = f;
  x.i += 0x7fff + ((x.i >> 16) & 1);   // RNE
  return (unsigned short)(x.i >> 16);
}
__device__ __forceinline__ float phi(float x){
  return x > 0.f ? x + 1.f : __expf(x);
}
__device__ __forceinline__ void gll16(const void* g, void* l){
  __builtin_amdgcn_global_load_lds((const __attribute__((address_space(1))) unsigned int*)g,
      (__attribute__((address_space(3))) unsigned int*)l, 16, 0, 0);
}

// ---------- MFMA GEMM (projections + W2): C[M,N] = act(A[M,K] @ Bt[N,K]^T) ----------
// R0-proven config: 128x128 tile, 256 threads, grid (N/128, M/128), db BK=32, drain-at-top.
template<typename TC, bool RELU>
__global__ __launch_bounds__(256) void gemm_mfma(const unsigned short* __restrict__ A,
                                                 const unsigned short* __restrict__ Bt,
                                                 TC* __restrict__ C, int M, int N, int K){
  __shared__ unsigned short Al[2][4096];   // [buf][128 rows][32 k]
  __shared__ unsigned short Bl[2][4096];
  const int tid  = threadIdx.x;
  const int lane = tid & 63;
  const int wave = tid >> 6;
  const int row0 = blockIdx.y << 7;
  const int col0 = blockIdx.x << 7;
  const int wr0  = (wave & 1) << 6;
  const int wc0  = (wave >> 1) << 6;
  const int m = lane & 15, q = lane >> 4;
  const int sw = (m >> 1) & 3;

  floatx4 acc[4][4] = {};

  const int u0 = tid, u1 = tid + 256;
  const int r0 = u0 >> 2, s0 = u0 & 3;
  const int r1 = u1 >> 2, s1 = u1 & 3;

  auto stage = [&](int k0, int b){
    gll16(A  + (size_t)(row0 + r0)*K + k0 + ((s0 ^ ((r0 >> 1) & 3)) << 3), Al[b] + (size_t)u0*8);
    gll16(A  + (size_t)(row0 + r1)*K + k0 + ((s1 ^ ((r1 >> 1) & 3)) << 3), Al[b] + (size_t)u1*8);
    gll16(Bt + (size_t)(col0 + r0)*K + k0 + ((s0 ^ ((r0 >> 1) & 3)) << 3), Bl[b] + (size_t)u0*8);
    gll16(Bt + (size_t)(col0 + r1)*K + k0 + ((s1 ^ ((r1 >> 1) & 3)) << 3), Bl[b] + (size_t)u1*8);
  };

  stage(0, 0);
  const int nk = K >> 5;
  for (int ks = 0; ks < nk; ks++){
    asm volatile("s_waitcnt vmcnt(0) lgkmcnt(0)" ::: "memory");
    __builtin_amdgcn_s_barrier();
    asm volatile("" ::: "memory");
    if (ks < nk - 1) stage((ks + 1) << 5, (ks + 1) & 1);
    const unsigned short* ab = Al[ks & 1];
    const unsigned short* bb = Bl[ks & 1];
    bfrag8 af[4], bf[4];
    #pragma unroll
    for (int t = 0; t < 4; t++){
      af[t] = *(const bfrag8*)(ab + (size_t)(wr0 + t*16 + m)*32 + ((q ^ sw) << 3));
      bf[t] = *(const bfrag8*)(bb + (size_t)(wc0 + t*16 + m)*32 + ((q ^ sw) << 3));
    }
    #pragma unroll
    for (int mt = 0; mt < 4; mt++)
      #pragma unroll
      for (int nt = 0; nt < 4; nt++)
        acc[mt][nt] = __builtin_amdgcn_mfma_f32_16x16x32_bf16(af[mt], bf[nt], acc[mt][nt], 0, 0, 0);
  }

  #pragma unroll
  for (int mt = 0; mt < 4; mt++){
    #pragma unroll
    for (int nt = 0; nt < 4; nt++){
      const int col  = col0 + wc0 + nt*16 + m;
      const int rowb = row0 + wr0 + mt*16 + q*4;
      #pragma unroll
      for (int i = 0; i < 4; i++){
        float v = acc[mt][nt][i];
        if (RELU) v = v > 0.f ? v : 0.f;
        if constexpr (std::is_same<TC,float>::value) C[(size_t)(rowb+i)*N + col] = v;
        else                                         C[(size_t)(rowb+i)*N + col] = f2bf(v);
      }
    }
  }
}

// ---------- W1 GEMM with K-split A: hid = relu([xc | msgln] @ W1) ----------
// Identical proven structure to gemm_mfma; only the A source switches at k=256.
__global__ __launch_bounds__(256) void gemm_w1(const unsigned short* __restrict__ Axc,
                                               const unsigned short* __restrict__ Amsg,
                                               const unsigned short* __restrict__ Bt,
                                               unsigned short* __restrict__ C){
  __shared__ unsigned short Al[2][4096];
  __shared__ unsigned short Bl[2][4096];
  const int tid  = threadIdx.x;
  const int lane = tid & 63;
  const int wave = tid >> 6;
  const int row0 = blockIdx.y << 7;
  const int col0 = blockIdx.x << 7;
  const int wr0  = (wave & 1) << 6;
  const int wc0  = (wave >> 1) << 6;
  const int m = lane & 15, q = lane >> 4;
  const int sw = (m >> 1) & 3;
  const int K = 512;

  floatx4 acc[4][4] = {};

  const int u0 = tid, u1 = tid + 256;
  const int r0 = u0 >> 2, s0 = u0 & 3;
  const int r1 = u1 >> 2, s1 = u1 & 3;

  auto stage = [&](int ks, int b){
    const int k0 = ks << 5;
    const unsigned short* As = (ks < 8) ? Axc : Amsg;
    const int kk = k0 & 255;
    gll16(As + (size_t)(row0 + r0)*256 + kk + ((s0 ^ ((r0 >> 1) & 3)) << 3), Al[b] + (size_t)u0*8);
    gll16(As + (size_t)(row0 + r1)*256 + kk + ((s1 ^ ((r1 >> 1) & 3)) << 3), Al[b] + (size_t)u1*8);
    gll16(Bt + (size_t)(col0 + r0)*K + k0 + ((s0 ^ ((r0 >> 1) & 3)) << 3), Bl[b] + (size_t)u0*8);
    gll16(Bt + (size_t)(col0 + r1)*K + k0 + ((s1 ^ ((r1 >> 1) & 3)) << 3), Bl[b] + (size_t)u1*8);
  };

  stage(0, 0);
  for (int ks = 0; ks < 16; ks++){
    asm volatile("s_waitcnt vmcnt(0) lgkmcnt(0)" ::: "memory");
    __builtin_amdgcn_s_barrier();
    asm volatile("" ::: "memory");
    if (ks < 15) stage(ks + 1, (ks + 1) & 1);
    const unsigned short* ab = Al[ks & 1];
    const unsigned short* bb = Bl[ks & 1];
    bfrag8 af[4], bf[4];
    #pragma unroll
    for (int t = 0; t < 4; t++){
      af[t] = *(const bfrag8*)(ab + (size_t)(wr0 + t*16 + m)*32 + ((q ^ sw) << 3));
      bf[t] = *(const bfrag8*)(bb + (size_t)(wc0 + t*16 + m)*32 + ((q ^ sw) << 3));
    }
    #pragma unroll
    for (int mt = 0; mt < 4; mt++)
      #pragma unroll
      for (int nt = 0; nt < 4; nt++)
        acc[mt][nt] = __builtin_amdgcn_mfma_f32_16x16x32_bf16(af[mt], bf[nt], acc[mt][nt], 0, 0, 0);
  }

  #pragma unroll
  for (int mt = 0; mt < 4; mt++){
    #pragma unroll
    for (int nt = 0; nt < 4; nt++){
      const int col  = col0 + wc0 + nt*16 + m;
      const int rowb = row0 + wr0 + mt*16 + q*4;
      #pragma unroll
      for (int i = 0; i < 4; i++){
        float v = acc[mt][nt][i];
        v = v > 0.f ? v : 0.f;
        C[(size_t)(rowb+i)*512 + col] = f2bf(v);
      }
    }
  }
}

// ---------- GEMM + LN for Wm (R7 config, pair-merged): BK=64, 64x256 tile ----------
template<int MODE>
__global__ __launch_bounds__(256) void gemm_lnv2(const unsigned short* __restrict__ A0,
                                                 const unsigned short* __restrict__ A1,
                                                 const unsigned short* __restrict__ Bt,
                                                 const float* __restrict__ g,
                                                 const float* __restrict__ b,
                                                 unsigned short* __restrict__ ob0,
                                                 unsigned short* __restrict__ ob1,
                                                 float* __restrict__ of,
                                                 int K, int add){
  __shared__ unsigned short Ab[4096];     // 2 half-tiles x [64 r][32 k]
  __shared__ unsigned short Bb[16384];    // 2 half-tiles x [256 c][32 k]
  __shared__ float2 LNp[64][4];
  __shared__ float2 LNmu[64];
  const int tid = threadIdx.x;
  const int wv = tid >> 6, lane = tid & 63;
  const int m = lane & 15, qd = lane >> 4;
  const int sw = (m >> 1) & 3;
  const int row0 = blockIdx.x << 6;
  const unsigned short* A = (MODE == 0 && blockIdx.y) ? A1 : A0;
  unsigned short* ob = (MODE == 0 && blockIdx.y) ? ob1 : ob0;

  floatx4 acc[4][4] = {};
  const int nsteps = K >> 6;
  for (int o = 0; o < nsteps; o++){
    const int k0 = o << 6;
    #pragma unroll
    for (int i = 0; i < 2; i++){           // A: u in [0,512): [h][r][s]
      int u = (i << 8) + tid;
      int r = (u & 255) >> 2, s = u & 3, h = u >> 8;
      gll16(A + (size_t)(row0 + r)*K + k0 + h*32 + ((s ^ ((r >> 1) & 3)) << 3),
            Ab + (size_t)u*8);
    }
    #pragma unroll
    for (int i = 0; i < 8; i++){           // B: u in [0,2048): [h][c][s]
      int u = (i << 8) + tid;
      int c = (u & 1023) >> 2, s = u & 3, h = u >> 10;
      gll16(Bt + (size_t)c*K + k0 + h*32 + ((s ^ ((c >> 1) & 3)) << 3),
            Bb + (size_t)u*8);
    }
    asm volatile("s_waitcnt vmcnt(0)" ::: "memory");
    __syncthreads();
    #pragma unroll
    for (int j = 0; j < 2; j++){
      bfrag8 af[4], bf[4];
      #pragma unroll
      for (int mt = 0; mt < 4; mt++){
        int r = mt*16 + m;
        af[mt] = *(const bfrag8*)(Ab + (size_t)j*2048 + (size_t)r*32 + ((qd ^ sw) << 3));
      }
      #pragma unroll
      for (int nt = 0; nt < 4; nt++){
        int c = wv*64 + nt*16 + m;
        bf[nt] = *(const bfrag8*)(Bb + (size_t)j*8192 + (size_t)c*32 + ((qd ^ sw) << 3));
      }
      #pragma unroll
      for (int mt = 0; mt < 4; mt++)
        #pragma unroll
        for (int nt = 0; nt < 4; nt++)
          acc[mt][nt] = __builtin_amdgcn_mfma_f32_16x16x32_bf16(af[mt], bf[nt], acc[mt][nt], 0, 0, 0);
    }
    __syncthreads();
  }

  // ---- LN: per-wave partials over its 64 cols, merge across 4 waves ----
  #pragma unroll
  for (int mt = 0; mt < 4; mt++)
    #pragma unroll
    for (int i = 0; i < 4; i++){
      float s = 0.f, q = 0.f;
      #pragma unroll
      for (int nt = 0; nt < 4; nt++){ float v = acc[mt][nt][i]; s += v; q += v*v; }
      #pragma unroll
      for (int o = 1; o < 16; o <<= 1){ s += __shfl_xor(s, o, 64); q += __shfl_xor(q, o, 64); }
      if (m == 0) LNp[mt*16 + qd*4 + i][wv] = make_float2(s, q);
    }
  __syncthreads();
  if (tid < 64){
    float2 p0 = LNp[tid][0], p1 = LNp[tid][1], p2 = LNp[tid][2], p3 = LNp[tid][3];
    float S = p0.x + p1.x + p2.x + p3.x;
    float Q = p0.y + p1.y + p2.y + p3.y;
    float mean = S * (1.f/256.f);
    float var  = Q * (1.f/256.f) - mean*mean;
    LNmu[tid] = make_float2(mean, rsqrtf(var + 1e-5f));
  }
  __syncthreads();

  float gv[4], bv[4];
  #pragma unroll
  for (int nt = 0; nt < 4; nt++){ int col = wv*64 + nt*16 + m; gv[nt] = g[col]; bv[nt] = b[col]; }
  #pragma unroll
  for (int mt = 0; mt < 4; mt++)
    #pragma unroll
    for (int i = 0; i < 4; i++){
      int row = mt*16 + qd*4 + i;
      float2 ms = LNmu[row];
      const size_t rowg = row0 + row;
      #pragma unroll
      for (int nt = 0; nt < 4; nt++){
        int col = wv*64 + nt*16 + m;
        float y = (acc[mt][nt][i] - ms.x) * ms.y * gv[nt] + bv[nt];
        if constexpr (MODE == 0){
          ob[rowg*256 + col] = f2bf(y);
        } else {
          float* p = of + rowg*256 + col;
          if (add) y += *p;
          *p = y;
        }
      }
    }
}

// ---------- LayerNorm from bf16 input, accumulate into macc (wave-per-row) ----------
__device__ __forceinline__ float waveSum16(float v){
  #pragma unroll
  for (int o = 1; o < 16; o <<= 1) v += __shfl_xor(v, o, 64);
  return v;
}
__global__ __launch_bounds__(256) void ln_accb(const unsigned short* __restrict__ X,
                                               const float* __restrict__ g,
                                               const float* __restrict__ b,
                                               float* __restrict__ macc, int add){
  const int lane = threadIdx.x & 63;
  const int row = blockIdx.x*4 + (threadIdx.x >> 6);
  ushort4 u = ((const ushort4*)(X + (size_t)row*256))[lane];
  float x0 = bf2f(u.x), x1 = bf2f(u.y), x2 = bf2f(u.z), x3 = bf2f(u.w);
  // lane covers cols lane*4..lane*4+3; 64 lanes x 4 = 256. 16-lane butterfly insufficient -> need 64.
  float s = x0 + x1 + x2 + x3;
  float q = x0*x0 + x1*x1 + x2*x2 + x3*x3;
  #pragma unroll
  for (int o = 1; o < 64; o <<= 1){ s += __shfl_xor(s, o, 64); q += __shfl_xor(q, o, 64); }
  float mu = s * (1.f/256.f);
  float var = q * (1.f/256.f) - mu*mu;
  float rs = rsqrtf(var + 1e-5f);
  float4 gv = ((const float4*)g)[lane];
  float4 bv = ((const float4*)b)[lane];
  float4 y;
  y.x = (x0 - mu)*rs*gv.x + bv.x;
  y.y = (x1 - mu)*rs*gv.y + bv.y;
  y.z = (x2 - mu)*rs*gv.z + bv.z;
  y.w = (x3 - mu)*rs*gv.w + bv.w;
  float4* mp = (float4*)(macc + (size_t)row*256) + lane;
  if (add){
    float4 old = *mp;
    y.x += old.x; y.y += old.y; y.z += old.z; y.w += old.w;
  }
  *mp = y;
}

// ---------- one-time converts ----------
__global__ __launch_bounds__(256) void wconv(const float* __restrict__ W, unsigned short* __restrict__ Wt,
                                             int kshift, int N){
  int idx = blockIdx.x*256 + threadIdx.x;
  int kk = idx & ((1 << kshift) - 1);
  int nn = idx >> kshift;
  Wt[idx] = f2bf(W[(size_t)kk*N + nn]);
}
__global__ __launch_bounds__(256) void conv_bf16(const float* __restrict__ in, unsigned short* __restrict__ out){
  int i = blockIdx.x*256 + threadIdx.x;
  float4 v = ((const float4*)in)[i];
  ushort4 o; o.x = f2bf(v.x); o.y = f2bf(v.y); o.z = f2bf(v.z); o.w = f2bf(v.w);
  ((ushort4*)out)[i] = o;
}

// ---------- permute materializers ----------
__global__ __launch_bounds__(256) void permute1(const unsigned short* __restrict__ sA, unsigned short* __restrict__ dA,
                                                const unsigned short* __restrict__ sB, unsigned short* __restrict__ dB){
  const unsigned short* s = blockIdx.z ? sB : sA;
  unsigned short*       d = blockIdx.z ? dB : dA;
  __shared__ unsigned short tile[1024];
  const int t = threadIdx.x;
  const size_t base = (size_t)blockIdx.x * 1024;
  #pragma unroll
  for (int i = 0; i < 4; i++) tile[i*256 + t] = s[base + i*256 + t];
  __syncthreads();
  const int pg = ((t & 7) << 5) + (t >> 3);
  #pragma unroll
  for (int i = 0; i < 4; i++) d[base + i*256 + t] = tile[i*256 + pg];
}

__global__ __launch_bounds__(256) void permute2(const unsigned short* __restrict__ sA, unsigned short* __restrict__ dA,
                                                const unsigned short* __restrict__ sB, unsigned short* __restrict__ dB){
  const unsigned short* s = blockIdx.z ? sB : sA;
  unsigned short*       d = blockIdx.z ? dB : dA;
  __shared__ unsigned short tile[64*256];
  const int t = threadIdx.x;
  const int rr0 = blockIdx.x * 64;
  const size_t boff = (size_t)blockIdx.y * PERBATCH;
  #pragma unroll
  for (int i = 0; i < 16; i++){
    int u = i*256 + t;
    *(ushort4*)&tile[u*4] = *(const ushort4*)&s[boff + (size_t)rr0*256 + (size_t)u*4];
  }
  __syncthreads();
  #pragma unroll
  for (int i = 0; i < 8; i++){
    #pragma unroll
    for (int w = 0; w < 2; w++){
      int u = w*256 + t;
      int rr = u >> 3, c4 = (u & 7) << 2;
      ushort4 v = *(const ushort4*)&tile[rr*256 + i*32 + c4];
      *(ushort4*)&d[boff + (size_t)i*153600 + (size_t)rr0*32 + (size_t)u*4] = v;
    }
  }
}

__global__ __launch_bounds__(256) void permute3(const unsigned short* __restrict__ sA, unsigned short* __restrict__ dA,
                                                const unsigned short* __restrict__ sB, unsigned short* __restrict__ dB){
  const unsigned short* s = blockIdx.z ? sB : sA;
  unsigned short*       d = blockIdx.z ? dB : dA;
  __shared__ unsigned short tile[64*258];
  const int t = threadIdx.x;
  const int ll0 = blockIdx.x * 64;
  const size_t boff = (size_t)blockIdx.y * PERBATCH;
  #pragma unroll
  for (int i = 0; i < 32; i++){
    int u = i*256 + t;
    int row = u >> 7, col = (u & 127) << 1;
    *(ushort2*)&tile[row*258 + col] = *(const ushort2*)&s[boff + (size_t)(ll0+row)*256 + col];
  }
  __syncthreads();
  const int cw = t >> 6;
  const int ll = t & 63;
  #pragma unroll
  for (int cc = 0; cc < 256; cc += 4){
    int c = cc + cw;
    int sigma = ((c & 31) << 3) + (c >> 5);
    d[boff + (size_t)sigma*4800 + ll0 + ll] = tile[ll*258 + c];
  }
}

// ---------- attention phase A (KV/Ksum stats) ----------
__global__ __launch_bounds__(256) void attn_stats(const unsigned short* __restrict__ kq,
                                                  const unsigned short* __restrict__ vq,
                                                  float* __restrict__ KV, float* __restrict__ Ksum){
  const int chunk = blockIdx.x, h = blockIdx.y, n = blockIdx.z;
  const int t = threadIdx.x;
  const int d = t >> 3;
  const int w4 = (t & 7) << 2;
  const size_t boff = (size_t)n * PERBATCH;
  __shared__ float kb[8][32], vb[8][32];
  const int lr = t >> 5, lj = t & 31;
  float a0=0.f, a1=0.f, a2=0.f, a3=0.f, ks=0.f;
  const int s0 = chunk * 240;
  for (int s = s0; s < s0 + 240; s += 8){
    int srci = (s + lr)*256 + (h << 5) + lj;
    kb[lr][lj] = phi(bf2f(kq[boff + srci]));
    vb[lr][lj] = bf2f(vq[boff + srci]);
    __syncthreads();
    #pragma unroll
    for (int r = 0; r < 8; r++){
      float kd = kb[r][d];
      ks += kd;
      a0 += kd * vb[r][w4+0];
      a1 += kd * vb[r][w4+1];
      a2 += kd * vb[r][w4+2];
      a3 += kd * vb[r][w4+3];
    }
    __syncthreads();
  }
  float* kvp = KV + (size_t)((((n<<3)+h)<<5) + d)*32 + w4;
  atomicAdd(kvp+0, a0);
  atomicAdd(kvp+1, a1);
  atomicAdd(kvp+2, a2);
  atomicAdd(kvp+3, a3);
  if ((t & 7) == 0) atomicAdd(Ksum + (((n<<3)+h)<<5) + d, ks);
}

// ---------- attention phase B: 16 rows/block, KV cached in LDS (R0 proven) ----------
__global__ __launch_bounds__(256) void attn_apply(const unsigned short* __restrict__ qq,
                                                  const float* __restrict__ KV,
                                                  const float* __restrict__ Ksum,
                                                  unsigned short* __restrict__ msg){
  __shared__ float kvs[8192];   // [h][dd][w]
  __shared__ float kss[256];    // [h][dd]
  __shared__ float Qs[4096];    // [r][256], phi-applied
  const int t = threadIdx.x;
  const int n = blockIdx.y;
  const int row0 = blockIdx.x << 4;
  const size_t boff = (size_t)n * PERBATCH;

  #pragma unroll
  for (int i = 0; i < 32; i++) kvs[i*256 + t] = KV[(size_t)n*8192 + i*256 + t];
  kss[t] = Ksum[n*256 + t];
  #pragma unroll
  for (int r = 0; r < 16; r++)
    Qs[r*256 + t] = phi(bf2f(qq[boff + (size_t)(row0 + r)*256 + t]));
  __syncthreads();

  const int h = t >> 5, w = t & 31;
  const float* kvh = kvs + h*1024;
  const float* ksh = kss + h*32;
  float acc[16], den[16];
  #pragma unroll
  for (int r = 0; r < 16; r++){ acc[r] = 0.f; den[r] = 1e-6f; }

  #pragma unroll
  for (int d4 = 0; d4 < 8; d4++){
    const float k0 = kvh[(d4*4+0)*32 + w];
    const float k1 = kvh[(d4*4+1)*32 + w];
    const float k2 = kvh[(d4*4+2)*32 + w];
    const float k3 = kvh[(d4*4+3)*32 + w];
    const float s0 = ksh[d4*4+0], s1 = ksh[d4*4+1], s2 = ksh[d4*4+2], s3 = ksh[d4*4+3];
    #pragma unroll
    for (int r = 0; r < 16; r++){
      float4 qv = *(const float4*)&Qs[r*256 + h*32 + d4*4];
      acc[r] += qv.x*k0 + qv.y*k1 + qv.z*k2 + qv.w*k3;
      den[r] += qv.x*s0 + qv.y*s1 + qv.z*s2 + qv.w*s3;
    }
  }
  #pragma unroll
  for (int r = 0; r < 16; r++)
    msg[boff + (size_t)(row0 + r)*256 + t] = f2bf(acc[r]/den[r]);
}

// ---------- elementwise ----------
__global__ __launch_bounds__(256) void xmid_k(const float* __restrict__ x, const float* __restrict__ macc,
                                              float* __restrict__ xmid, unsigned short* __restrict__ xcbf){
  size_t i = (size_t)blockIdx.x*256 + threadIdx.x;
  float v = x[i] + 0.5f*macc[i];
  xmid[i] = v;
  xcbf[i] = f2bf(v);
}
__global__ __launch_bounds__(256) void final_k(float* __restrict__ out, const float* __restrict__ macc){
  size_t i = (size_t)blockIdx.x*256 + threadIdx.x;
  out[i] = out[i] + 0.5f*macc[i];
}
__global__ __launch_bounds__(256) void zero_k(float* __restrict__ p, int n){
  int i = blockIdx.x*256 + threadIdx.x;
  if (i < n) p[i] = 0.f;
}

// ---------- orchestration ----------
extern "C" void kernel_launch(void* const* d_in, const int* in_sizes, int n_in,
                              void* d_out, int out_size, void* d_ws, size_t ws_size,
                              hipStream_t stream){
  const float* x   = (const float*)d_in[0];
  const float* src = (const float*)d_in[1];
  const float* Wq  = (const float*)d_in[2];
  const float* Wk  = (const float*)d_in[3];
  const float* Wv  = (const float*)d_in[4];
  const float* Wm  = (const float*)d_in[5];
  const float* W1  = (const float*)d_in[6];
  const float* W2  = (const float*)d_in[7];
  const float* g1  = (const float*)d_in[8];
  const float* b1  = (const float*)d_in[9];
  const float* g2  = (const float*)d_in[10];
  const float* b2  = (const float*)d_in[11];
  float* out = (float*)d_out;

  char* ws = (char*)d_ws;
  size_t off = 0;
  auto alloc = [&](size_t bytes) -> void* {
    void* p = ws + off;
    off += (bytes + 255) & ~(size_t)255;
    return p;
  };
  unsigned short* qB   = (unsigned short*)alloc((size_t)MROWS*256*2);
  unsigned short* kB   = (unsigned short*)alloc((size_t)MROWS*256*2);   // msg slot A / hid lo
  unsigned short* vB   = (unsigned short*)alloc((size_t)MROWS*256*2);   // msg slot B / hid hi
  unsigned short* mlnB = (unsigned short*)alloc((size_t)MROWS*512*2);   // msgln0 | msgln1
  float* t1   = (float*)alloc((size_t)MROWS*256*4);                     // srcbf/qP,wout | xbf/xc
  float* macc = (float*)alloc((size_t)MROWS*256*4);
  float* KV4  = (float*)alloc((size_t)4*KVSET*4);
  unsigned short* WqT = (unsigned short*)alloc((size_t)256*256*2);
  unsigned short* WkT = (unsigned short*)alloc((size_t)256*256*2);
  unsigned short* WvT = (unsigned short*)alloc((size_t)256*256*2);
  unsigned short* WmT = (unsigned short*)alloc((size_t)256*256*2);
  unsigned short* W1T = (unsigned short*)alloc((size_t)512*512*2);
  unsigned short* W2T = (unsigned short*)alloc((size_t)256*512*2);
  (void)ws_size; (void)in_sizes; (void)n_in; (void)out_size;

  unsigned short* srcbf  = (unsigned short*)t1;
  unsigned short* xcbf   = srcbf + (size_t)MROWS*256;    // x bf16, later xmid bf16
  unsigned short* qP     = (unsigned short*)t1;          // permuted q (dead after attn_apply)
  unsigned short* wout   = (unsigned short*)t1;          // W2 bf16 output (same region, after qP dead)
  unsigned short* msgln0 = mlnB;
  unsigned short* msgln1 = mlnB + (size_t)MROWS*256;
  unsigned short* hid    = kB;                           // 39.3MB spanning kB+vB
  float* xmid = out;

  const dim3 blk(256);

  wconv<<<dim3(256),  blk, 0, stream>>>(Wq, WqT, 8, 256);
  wconv<<<dim3(256),  blk, 0, stream>>>(Wk, WkT, 8, 256);
  wconv<<<dim3(256),  blk, 0, stream>>>(Wv, WvT, 8, 256);
  wconv<<<dim3(256),  blk, 0, stream>>>(Wm, WmT, 8, 256);
  wconv<<<dim3(1024), blk, 0, stream>>>(W1, W1T, 9, 512);
  wconv<<<dim3(512),  blk, 0, stream>>>(W2, W2T, 9, 256);
  conv_bf16<<<dim3(9600), blk, 0, stream>>>(src, srcbf);
  conv_bf16<<<dim3(9600), blk, 0, stream>>>(x,   xcbf);

  gemm_mfma<unsigned short, false><<<dim3(2,300), blk, 0, stream>>>(xcbf,  WqT, qB, MROWS, 256, 256);
  gemm_mfma<unsigned short, false><<<dim3(2,300), blk, 0, stream>>>(srcbf, WkT, kB, MROWS, 256, 256);
  gemm_mfma<unsigned short, false><<<dim3(2,300), blk, 0, stream>>>(srcbf, WvT, vB, MROWS, 256, 256);

  // all-mode stats upfront; permuted k/v live in macc space (dead until first ln_accb)
  unsigned short* kP = (unsigned short*)macc;
  unsigned short* vP = kP + (size_t)MROWS*256;
  zero_k<<<dim3(1056), blk, 0, stream>>>(KV4, 4*KVSET);
  attn_stats<<<dim3(20,8,8), blk, 0, stream>>>(kB, vB, KV4 + 0*KVSET, KV4 + 0*KVSET + 65536);
  permute1<<<dim3(9600,1,2), blk, 0, stream>>>(kB, kP, vB, vP);
  attn_stats<<<dim3(20,8,8), blk, 0, stream>>>(kP, vP, KV4 + 1*KVSET, KV4 + 1*KVSET + 65536);
  permute2<<<dim3(75,8,2),  blk, 0, stream>>>(kB, kP, vB, vP);
  attn_stats<<<dim3(20,8,8), blk, 0, stream>>>(kP, vP, KV4 + 2*KVSET, KV4 + 2*KVSET + 65536);
  permute3<<<dim3(75,8,2),  blk, 0, stream>>>(kB, kP, vB, vP);
  attn_stats<<<dim3(20,8,8), blk, 0, stream>>>(kP, vP, KV4 + 3*KVSET, KV4 + 3*KVSET + 65536);

  auto run_pair = [&](int modeA, int modeB, int addA){
    // attention for both modes of the pair -> msg in kB / vB
    {
      const float* KV = KV4 + (size_t)modeA*KVSET;
      const unsigned short* qsrc = qB;
      if (modeA == 2){ permute2<<<dim3(75,8,1), blk, 0, stream>>>(qB, qP, nullptr, nullptr); qsrc = qP; }
      attn_apply<<<dim3(300,BS), blk, 0, stream>>>(qsrc, KV, KV + 65536, kB);
    }
    {
      const float* KV = KV4 + (size_t)modeB*KVSET;
      if (modeB == 1)      permute1<<<dim3(9600,1,1), blk, 0, stream>>>(qB, qP, nullptr, nullptr);
      else                 permute3<<<dim3(75,8,1),   blk, 0, stream>>>(qB, qP, nullptr, nullptr);
      attn_apply<<<dim3(300,BS), blk, 0, stream>>>(qP, KV, KV + 65536, vB);
    }
    // merged Wm GEMM + LN for both modes -> msgln0/msgln1 (qP now dead -> wout region free)
    gemm_lnv2<0><<<dim3(600,2), blk, 0, stream>>>(kB, vB, WmT, g1, b1, msgln0, msgln1, nullptr, 256, 0);
    // FFN chains (serial: hid buffer shared); W2 = proven 128x128 gemm + separate LN
    gemm_w1<<<dim3(4,300), blk, 0, stream>>>(xcbf, msgln0, W1T, hid);
    gemm_mfma<unsigned short, false><<<dim3(2,300), blk, 0, stream>>>(hid, W2T, wout, MROWS, 256, 512);
    ln_accb<<<dim3(9600), blk, 0, stream>>>(wout, g2, b2, macc, addA);
    gemm_w1<<<dim3(4,300), blk, 0, stream>>>(xcbf, msgln1, W1T, hid);
    gemm_mfma<unsigned short, false><<<dim3(2,300), blk, 0, stream>>>(hid, W2T, wout, MROWS, 256, 512);
    ln_accb<<<dim3(9600), blk, 0, stream>>>(wout, g2, b2, macc, 1);
  };

  run_pair(0, 1, 0);                                            // m, m3
  xmid_k<<<dim3(MROWS), blk, 0, stream>>>(x, macc, xmid, xcbf); // xmid + xc update
  run_pair(2, 3, 0);                                            // m1, m2
  final_k<<<dim3(MROWS), blk, 0, stream>>>(out, macc);
}